// Round 18
// baseline (22.065 us; speedup 1.0000x reference)
//
#include <hip/hip_runtime.h>

#define HW       16384                  // 128*128
#define NCLASS   121

// d_out layout (flat f32, return order: pred, m_mask, disappear, appear)
#define OFF_PRED 0
#define OFF_MASK (8 * 3 * HW)                    // 393216
#define OFF_DIS  (OFF_MASK + 8 * NCLASS * HW)    // 16252928
#define OFF_APP  (OFF_DIS + 8 * HW)              // 16384000

#define NSEGBLK  256             // k_seg: per batch, 32 row-tiles (128x4)
#define NPREDBLK 768             // fused: 3 channels x 256 tiles (128x4), FIRST
#define NMASKBLK (8 * 16 * 11)   // 1408: per batch, 16 row-tiles (128x8), 11 kb

#define SENT 100000.0f           // OOB sentinel: floor->100000, all targets rejected

typedef float nfloat4 __attribute__((ext_vector_type(4)));

__device__ __forceinline__ float hatf(float u) { return fmaxf(0.f, 1.f - fabsf(u)); }

__device__ __forceinline__ void nt_store4(float* p, float a, float b, float c, float d) {
    nfloat4 nv; nv.x = a; nv.y = b; nv.z = c; nv.w = d;
    __builtin_nontemporal_store(nv, (nfloat4*)p);
}

// K1: seg scatter in LDS for a 128x4 tile -> dis/app writes.
// Halo = 14 rows x 128 = 448 float4; thread t takes float4 #t and #(256+t).
// 4 wide loads/thread (was 14 scalar) -> short latency chain, coalesced 1KB/wave.
__global__ __launch_bounds__(256) void k_seg(const float* __restrict__ motion,
                                             float* __restrict__ out) {
    __shared__ float sseg[4 * 128];     // 2 KB
    int blk = blockIdx.x;               // 0..255
    int b   = blk >> 5;
    int y0  = (blk & 31) << 2;
    int tid = threadIdx.x;

    const float* motx = motion + (size_t)(b * 2) * HW;
    const float* moty = motx + HW;

    float4 mx4[2], my4[2];
    int syv[2], sxv[2];
    #pragma unroll
    for (int g = 0; g < 2; ++g) {
        int idx4 = g * 256 + tid;            // 0..511; valid < 448
        int r    = idx4 >> 5;                // halo row 0..13 (valid)
        int sx   = (idx4 & 31) << 2;
        int sy   = y0 - 5 + r;
        bool ok  = (idx4 < 448) && (sy >= 0) && (sy < 128);
        int s    = (ok ? sy : 0) * 128 + sx;
        float4 a = *(const float4*)(motx + s);
        float4 c = *(const float4*)(moty + s);
        float4 sn = make_float4(SENT, SENT, SENT, SENT);
        mx4[g] = ok ? a : sn;
        my4[g] = ok ? c : sn;
        syv[g] = sy; sxv[g] = sx;
    }
    asm volatile("" ::: "memory");

    ((float2*)sseg)[tid] = make_float2(0.f, 0.f);
    __syncthreads();

    #pragma unroll
    for (int g = 0; g < 2; ++g) {
        const float* mxp = (const float*)&mx4[g];
        const float* myp = (const float*)&my4[g];
        int sy = syv[g];
        #pragma unroll
        for (int p = 0; p < 4; ++p) {
            float mx = mxp[p], my = myp[p];
            int sx = sxv[g] + p;
            float flx = floorf(mx), fly = floorf(my);
            float fa = mx - flx, fb = my - fly;
            int ia = (int)flx + 5, ib = (int)fly + 5;
            float wa0 = 1.f - fa, wa1 = fa;
            float wb0 = 1.f - fb, wb1 = fb;
            #pragma unroll
            for (int j = 0; j < 2; ++j) {
                int ty = sy - (ib + j) + 5;
                if (ty < y0 || ty >= y0 + 4) continue;
                float wb = j ? wb1 : wb0;
                #pragma unroll
                for (int i = 0; i < 2; ++i) {
                    int tx = sx - (ia + i) + 5;
                    if (tx < 0 || tx >= 128) continue;
                    atomicAdd(&sseg[(ty - y0) * 128 + tx], wb * (i ? wa1 : wa0));
                }
            }
        }
    }
    __syncthreads();

    int p2 = tid * 2;
    int ly = p2 >> 7;
    int x  = p2 & 127;
    float2 s2 = *(float2*)&sseg[ly * 128 + x];
    float2 d2, a2;
    d2.x = fmaxf(s2.x - 1.f, 0.f); a2.x = fmaxf(1.f - s2.x, 0.f);
    d2.y = fmaxf(s2.y - 1.f, 0.f); a2.y = fmaxf(1.f - s2.y, 0.f);
    int p = b * HW + (y0 + ly) * 128 + x;
    *(float2*)(out + OFF_DIS + p) = d2;
    *(float2*)(out + OFF_APP + p) = a2;
}

// K2 (fused): blk < NPREDBLK -> pred role, ONE channel per block, float4-wide
// prefetch (8 loads/thread, was 28 scalar); blk >= NPREDBLK -> mask role (NT).
__global__ __launch_bounds__(256) void k_maskpred(const float* __restrict__ motion,
                                                  const float* __restrict__ im_input,
                                                  float* __restrict__ out) {
    __shared__ float spred[4 * 128];    // 2 KB (pred role only)
    int tid = threadIdx.x;
    int blk = blockIdx.x;

    if (blk < NPREDBLK) {
        // ---- pred tile 128x4, channel c ----
        int c  = blk >> 8;               // 0..2
        int t  = blk & 255;
        int b  = t >> 5;
        int y0 = (t & 31) << 2;
        const float* motx = motion + (size_t)(b * 2) * HW;
        const float* moty = motx + HW;
        const float* imc  = im_input + (size_t)(b * 6 + 3 + c) * HW;
        const float* disb = out + OFF_DIS + (size_t)b * HW;

        float4 mx4[2], my4[2], im4[2], ds4[2];
        int syv[2], sxv[2];
        #pragma unroll
        for (int g = 0; g < 2; ++g) {
            int idx4 = g * 256 + tid;        // 0..511; valid < 448
            int r    = idx4 >> 5;
            int sx   = (idx4 & 31) << 2;
            int sy   = y0 - 5 + r;
            bool ok  = (idx4 < 448) && (sy >= 0) && (sy < 128);
            int s    = (ok ? sy : 0) * 128 + sx;
            float4 a = *(const float4*)(motx + s);
            float4 cc = *(const float4*)(moty + s);
            float4 e = *(const float4*)(imc + s);
            float4 d = *(const float4*)(disb + s);
            float4 sn = make_float4(SENT, SENT, SENT, SENT);
            float4 z  = make_float4(0.f, 0.f, 0.f, 0.f);
            mx4[g] = ok ? a : sn;
            my4[g] = ok ? cc : sn;
            im4[g] = ok ? e : z;
            ds4[g] = ok ? d : z;
            syv[g] = sy; sxv[g] = sx;
        }
        asm volatile("" ::: "memory");

        ((float2*)spred)[tid] = make_float2(0.f, 0.f);
        __syncthreads();

        #pragma unroll
        for (int g = 0; g < 2; ++g) {
            const float* mxp = (const float*)&mx4[g];
            const float* myp = (const float*)&my4[g];
            const float* imp = (const float*)&im4[g];
            const float* dsp = (const float*)&ds4[g];
            int sy = syv[g];
            #pragma unroll
            for (int p = 0; p < 4; ++p) {
                float mx = mxp[p], my = myp[p];
                float iv = imp[p] * (1.f - dsp[p]);
                int sx = sxv[g] + p;
                float flx = floorf(mx), fly = floorf(my);
                float fa = mx - flx, fb = my - fly;
                int ia = (int)flx + 5, ib = (int)fly + 5;
                float wa0 = 1.f - fa, wa1 = fa;
                float wb0 = 1.f - fb, wb1 = fb;
                #pragma unroll
                for (int j = 0; j < 2; ++j) {
                    int ty = sy - (ib + j) + 5;
                    if (ty < y0 || ty >= y0 + 4) continue;
                    float wb = j ? wb1 : wb0;
                    #pragma unroll
                    for (int i = 0; i < 2; ++i) {
                        int tx = sx - (ia + i) + 5;
                        if (tx < 0 || tx >= 128) continue;
                        atomicAdd(&spred[(ty - y0) * 128 + tx], wb * (i ? wa1 : wa0) * iv);
                    }
                }
            }
        }
        __syncthreads();

        // store 4 rows x 128 of channel c: 2 px/thread
        int p2 = tid * 2;
        int ly = p2 >> 7;
        int x  = p2 & 127;
        float2 v = *(float2*)&spred[ly * 128 + x];
        float* predb = out + OFF_PRED + (size_t)(b * 3 + c) * HW + (y0 + ly) * 128 + x;
        *(float2*)predb = v;
    } else {
        // ---- mask role: write m_mask channel-row kb over a 128x8 tile ----
        int mb = blk - NPREDBLK;         // 0..1407
        int kb = mb % 11;
        int tl = mb / 11;                // 0..127
        int b  = tl >> 4;
        int y0 = (tl & 15) << 3;
        const float* motx = motion + (size_t)(b * 2) * HW;
        const float* moty = motx + HW;

        int ly = tid >> 5;               // 0..7
        int x4 = (tid & 31) << 2;        // 0,4,...,124
        int g  = (y0 + ly) * 128 + x4;
        float4 mx = *(const float4*)(motx + g);
        float4 my = *(const float4*)(moty + g);
        float kbo = (float)(kb - 5);
        float4 bv;
        bv.x = hatf(my.x - kbo); bv.y = hatf(my.y - kbo);
        bv.z = hatf(my.z - kbo); bv.w = hatf(my.w - kbo);
        float* mm = out + OFF_MASK + ((size_t)(b * NCLASS + kb * 11)) * HW + g;
        #pragma unroll
        for (int ka = 0; ka < 11; ++ka) {
            float kao = (float)(ka - 5);
            nt_store4(mm + (size_t)ka * HW,
                      bv.x * hatf(mx.x - kao),
                      bv.y * hatf(mx.y - kao),
                      bv.z * hatf(mx.z - kao),
                      bv.w * hatf(mx.w - kao));
        }
    }
}

extern "C" void kernel_launch(void* const* d_in, const int* in_sizes, int n_in,
                              void* d_out, int out_size, void* d_ws, size_t ws_size,
                              hipStream_t stream) {
    const float* im_input = (const float*)d_in[0];   // (8, 6, 128, 128)
    const float* motion   = (const float*)d_in[1];   // (8, 2, 128, 128)
    // d_in[2] = m_kernel: identity by construction, unused.
    float* out = (float*)d_out;

    k_seg<<<dim3(NSEGBLK), dim3(256), 0, stream>>>(motion, out);
    k_maskpred<<<dim3(NPREDBLK + NMASKBLK), dim3(256), 0, stream>>>(motion, im_input, out);
}

// Round 19
// 21.933 us; speedup vs baseline: 1.0060x; 1.0060x over previous
//
#include <hip/hip_runtime.h>

#define HW       16384                  // 128*128
#define NCLASS   121

// d_out layout (flat f32, return order: pred, m_mask, disappear, appear)
#define OFF_PRED 0
#define OFF_MASK (8 * 3 * HW)                    // 393216
#define OFF_DIS  (OFF_MASK + 8 * NCLASS * HW)    // 16252928
#define OFF_APP  (OFF_DIS + 8 * HW)              // 16384000

#define NPREDBLK 768             // L2: 3 channels x 256 tiles (128x4), 512t, FIRST
#define NMASKBLK (8 * 8 * 11)    // 704: per batch, 8 row-tiles (128x16), 11 kb, 512t

#define SENT 100000.0f           // OOB sentinel: floor->100000, all targets rejected

typedef float nfloat4 __attribute__((ext_vector_type(4)));

__device__ __forceinline__ float hatf(float u) { return fmaxf(0.f, 1.f - fabsf(u)); }

__device__ __forceinline__ void nt_store4(float* p, float a, float b, float c, float d) {
    nfloat4 nv; nv.x = a; nv.y = b; nv.z = c; nv.w = d;
    __builtin_nontemporal_store(nv, (nfloat4*)p);
}

// K1: seg for ONE row. 1024 blocks = 8 batches x 128 rows; 11-row halo;
// LDS scatter; write dis/app for the row. ~4x the parallelism of the 4-row tile.
__global__ __launch_bounds__(256) void k_seg(const float* __restrict__ motion,
                                             float* __restrict__ out) {
    __shared__ float sseg[128];
    int tid = threadIdx.x;
    int blk = blockIdx.x;               // 0..1023
    int b   = blk >> 7;
    int y0  = blk & 127;

    const float* motx = motion + (size_t)(b * 2) * HW;
    const float* moty = motx + HW;

    // halo 11 rows x 128 = 352 float4; groups g=0 (tid) and g=1 (256+tid, tail)
    float4 mx4[2], my4[2];
    int syv[2], sxv[2];
    #pragma unroll
    for (int g = 0; g < 2; ++g) {
        int idx4 = g * 256 + tid;            // 0..511; valid < 352
        int r    = idx4 >> 5;
        int sx   = (idx4 & 31) << 2;
        int sy   = y0 - 5 + r;
        bool ok  = (idx4 < 352) && (sy >= 0) && (sy < 128);
        int s    = (ok ? sy : 0) * 128 + sx;
        float4 a = *(const float4*)(motx + s);
        float4 c = *(const float4*)(moty + s);
        float4 sn = make_float4(SENT, SENT, SENT, SENT);
        mx4[g] = ok ? a : sn;
        my4[g] = ok ? c : sn;
        syv[g] = sy; sxv[g] = sx;
    }

    if (tid < 128) sseg[tid] = 0.f;
    __syncthreads();

    #pragma unroll
    for (int g = 0; g < 2; ++g) {
        const float* mxp = (const float*)&mx4[g];
        const float* myp = (const float*)&my4[g];
        int sy = syv[g];
        #pragma unroll
        for (int p = 0; p < 4; ++p) {
            float mx = mxp[p], my = myp[p];
            int sx = sxv[g] + p;
            float flx = floorf(mx), fly = floorf(my);
            float fa = mx - flx, fb = my - fly;
            int ia = (int)flx + 5, ib = (int)fly + 5;
            float wa0 = 1.f - fa, wa1 = fa;
            float wb0 = 1.f - fb, wb1 = fb;
            #pragma unroll
            for (int j = 0; j < 2; ++j) {
                int ty = sy - (ib + j) + 5;
                if (ty != y0) continue;
                float wb = j ? wb1 : wb0;
                #pragma unroll
                for (int i = 0; i < 2; ++i) {
                    int tx = sx - (ia + i) + 5;
                    if (tx < 0 || tx >= 128) continue;
                    atomicAdd(&sseg[tx], wb * (i ? wa1 : wa0));
                }
            }
        }
    }
    __syncthreads();

    if (tid < 128) {
        float v = sseg[tid];
        int p = b * HW + y0 * 128 + tid;
        out[OFF_DIS + p] = fmaxf(v - 1.f, 0.f);
        out[OFF_APP + p] = fmaxf(1.f - v, 0.f);
    }
}

// K2 (fused, 512 threads): blk < NPREDBLK -> pred role (channel-split 128x4
// tile, 4 source iterations/thread); else mask role (128x16 tile, 11 kb).
__global__ __launch_bounds__(512) void k_maskpred(const float* __restrict__ motion,
                                                  const float* __restrict__ im_input,
                                                  float* __restrict__ out) {
    __shared__ float spred[4 * 128];    // 2 KB (pred role only)
    int tid = threadIdx.x;
    int blk = blockIdx.x;

    if (blk < NPREDBLK) {
        // ---- pred tile 128x4, channel c, 512 threads ----
        int c  = blk >> 8;               // 0..2
        int t  = blk & 255;
        int b  = t >> 5;
        int y0 = (t & 31) << 2;
        const float* motx = motion + (size_t)(b * 2) * HW;
        const float* moty = motx + HW;
        const float* imc  = im_input + (size_t)(b * 6 + 3 + c) * HW;
        const float* disb = out + OFF_DIS + (size_t)b * HW;

        // sources: 14 rows x 128 = 1792 px; 512 threads -> 4 guarded iterations
        float mxv[4], myv[4], imv[4], dsv[4];
        #pragma unroll
        for (int it = 0; it < 4; ++it) {
            int idx = tid + it * 512;        // 0..2047; valid < 1792
            int sy  = y0 - 5 + (idx >> 7);
            int sx  = idx & 127;
            bool ok = (idx < 1792) && (sy >= 0) && (sy < 128);
            int s   = (ok ? sy : 0) * 128 + sx;
            float mx = motx[s];
            float my = moty[s];
            float im = imc[s];
            float ds = disb[s];
            mxv[it] = ok ? mx : SENT;
            myv[it] = ok ? my : SENT;
            imv[it] = ok ? im : 0.f;
            dsv[it] = ds;
        }

        spred[tid] = 0.f;
        __syncthreads();

        #pragma unroll
        for (int it = 0; it < 4; ++it) {
            int idx = tid + it * 512;
            int sy  = y0 - 5 + (idx >> 7);
            int sx  = idx & 127;
            float mx = mxv[it], my = myv[it];
            float iv = imv[it] * (1.f - dsv[it]);
            float flx = floorf(mx), fly = floorf(my);
            float fa = mx - flx, fb = my - fly;
            int ia = (int)flx + 5, ib = (int)fly + 5;
            float wa0 = 1.f - fa, wa1 = fa;
            float wb0 = 1.f - fb, wb1 = fb;
            #pragma unroll
            for (int j = 0; j < 2; ++j) {
                int ty = sy - (ib + j) + 5;
                if (ty < y0 || ty >= y0 + 4) continue;
                float wb = j ? wb1 : wb0;
                #pragma unroll
                for (int i = 0; i < 2; ++i) {
                    int tx = sx - (ia + i) + 5;
                    if (tx < 0 || tx >= 128) continue;
                    atomicAdd(&spred[(ty - y0) * 128 + tx], wb * (i ? wa1 : wa0) * iv);
                }
            }
        }
        __syncthreads();

        // store 4 rows x 128 of channel c: 1 px/thread
        int ly = tid >> 7;
        int x  = tid & 127;
        out[OFF_PRED + (size_t)(b * 3 + c) * HW + (y0 + ly) * 128 + x] = spred[tid];
    } else {
        // ---- mask role: m_mask channel-row kb over a 128x16 tile, 512 threads ----
        int mb = blk - NPREDBLK;         // 0..703
        int kb = mb % 11;
        int tl = mb / 11;                // 0..63
        int b  = tl >> 3;
        int y0 = (tl & 7) << 4;          // 0,16,...,112
        const float* motx = motion + (size_t)(b * 2) * HW;
        const float* moty = motx + HW;

        int ly = tid >> 5;               // 0..15
        int x4 = (tid & 31) << 2;        // 0,4,...,124
        int g  = (y0 + ly) * 128 + x4;
        float4 mx = *(const float4*)(motx + g);
        float4 my = *(const float4*)(moty + g);
        float kbo = (float)(kb - 5);
        float4 bv;
        bv.x = hatf(my.x - kbo); bv.y = hatf(my.y - kbo);
        bv.z = hatf(my.z - kbo); bv.w = hatf(my.w - kbo);
        float* mm = out + OFF_MASK + ((size_t)(b * NCLASS + kb * 11)) * HW + g;
        #pragma unroll
        for (int ka = 0; ka < 11; ++ka) {
            float kao = (float)(ka - 5);
            nt_store4(mm + (size_t)ka * HW,
                      bv.x * hatf(mx.x - kao),
                      bv.y * hatf(mx.y - kao),
                      bv.z * hatf(mx.z - kao),
                      bv.w * hatf(mx.w - kao));
        }
    }
}

extern "C" void kernel_launch(void* const* d_in, const int* in_sizes, int n_in,
                              void* d_out, int out_size, void* d_ws, size_t ws_size,
                              hipStream_t stream) {
    const float* im_input = (const float*)d_in[0];   // (8, 6, 128, 128)
    const float* motion   = (const float*)d_in[1];   // (8, 2, 128, 128)
    // d_in[2] = m_kernel: identity by construction, unused.
    float* out = (float*)d_out;

    k_seg<<<dim3(1024), dim3(256), 0, stream>>>(motion, out);
    k_maskpred<<<dim3(NPREDBLK + NMASKBLK), dim3(512), 0, stream>>>(motion, im_input, out);
}